// Round 5
// baseline (1248.593 us; speedup 1.0000x reference)
//
#include <hip/hip_runtime.h>
#include <hip/hip_fp16.h>
#include <math.h>

#define NN 100000
#define EE 1600000
#define HH 64
#define LL 8
#define NBLK ((NN + 1023) / 1024)

__device__ __forceinline__ float eluf(float x) { return x > 0.0f ? x : expm1f(x); }

// ---------------- CSR build ----------------

__global__ void count_edges_k(const int* __restrict__ dst, int* __restrict__ counts) {
    int i = blockIdx.x * blockDim.x + threadIdx.x;
    if (i < EE) atomicAdd(&counts[dst[i]], 1);
}

__global__ void scan_block_k(const int* __restrict__ counts, int* __restrict__ rp,
                             int* __restrict__ partial, float* __restrict__ dinv) {
    __shared__ int sm[256];
    int t = threadIdx.x;
    int base = blockIdx.x * 1024 + t * 4;
    int v0 = 0, v1 = 0, v2 = 0, v3 = 0;
    if (base + 0 < NN) v0 = counts[base + 0];
    if (base + 1 < NN) v1 = counts[base + 1];
    if (base + 2 < NN) v2 = counts[base + 2];
    if (base + 3 < NN) v3 = counts[base + 3];
    if (base + 0 < NN) dinv[base + 0] = rsqrtf((float)(v0 + 1));
    if (base + 1 < NN) dinv[base + 1] = rsqrtf((float)(v1 + 1));
    if (base + 2 < NN) dinv[base + 2] = rsqrtf((float)(v2 + 1));
    if (base + 3 < NN) dinv[base + 3] = rsqrtf((float)(v3 + 1));
    int s = v0 + v1 + v2 + v3;
    sm[t] = s;
    __syncthreads();
    for (int off = 1; off < 256; off <<= 1) {
        int x = 0;
        if (t >= off) x = sm[t - off];
        __syncthreads();
        if (t >= off) sm[t] += x;
        __syncthreads();
    }
    int excl = sm[t] - s;
    if (t == 255) partial[blockIdx.x] = sm[255];
    if (base + 0 < NN) rp[base + 0] = excl;
    excl += v0;
    if (base + 1 < NN) rp[base + 1] = excl;
    excl += v1;
    if (base + 2 < NN) rp[base + 2] = excl;
    excl += v2;
    if (base + 3 < NN) rp[base + 3] = excl;
}

__global__ void scan_top_k(int* partial) {
    __shared__ int sm[128];
    int t = threadIdx.x;
    int v = (t < NBLK) ? partial[t] : 0;
    sm[t] = v;
    __syncthreads();
    for (int off = 1; off < 128; off <<= 1) {
        int x = 0;
        if (t >= off) x = sm[t - off];
        __syncthreads();
        if (t >= off) sm[t] += x;
        __syncthreads();
    }
    if (t < NBLK) partial[t] = sm[t] - v;  // exclusive
}

__global__ void scan_add_k(int* rp, const int* __restrict__ partial) {
    int i = blockIdx.x * blockDim.x + threadIdx.x;
    if (i < NN) rp[i] += partial[i >> 10];
    else if (i == NN) rp[NN] = EE;
}

// col-only payload (4B random write per edge; val factored out via pre-scaled rows)
__global__ void scatter_k(const int* __restrict__ src, const int* __restrict__ dst,
                          const int* __restrict__ rp, int* __restrict__ fill,
                          int* __restrict__ col) {
    int e = blockIdx.x * blockDim.x + threadIdx.x;
    if (e < EE) {
        int d = dst[e];
        int pos = rp[d] + atomicAdd(&fill[d], 1);
        col[pos] = src[e];
    }
}

// zero the sentinel row NN of both fp16 gather buffers (masked lanes gather row NN)
__global__ void init_sent_k(__half* a, __half* b) {
    int t = threadIdx.x;
    if (t < 64) a[(size_t)NN * HH + t] = __float2half(0.f);
    else b[(size_t)NN * HH + (t - 64)] = __float2half(0.f);
}

// ---------------- fused layer: s = 0.5*di*(sum h~[src] + h~[self]) + 0.5*x0;
//                  o = s @ (beta*W + (1-beta)*I);  h = elu(o)+o;
//                  hout16 = half(di*h)  [pre-scaled for next gather]; opt fp32 h ----------------
// One wave per node. 8 groups of 8 lanes; each lane covers an 8-feature chunk via
// 16B fp16 loads; two edge-rows in flight per inner iteration. Grid-stride over
// nodes amortizes the 16KB B-hat LDS staging.

__global__ __launch_bounds__(256) void layer_k(
    const int* __restrict__ rp, const int* __restrict__ col, const float* __restrict__ dinv,
    const __half* __restrict__ hin, const float* __restrict__ x0, const float* __restrict__ W,
    float beta, __half* __restrict__ hout, float* __restrict__ hout32, int w32) {
    __shared__ float Bs[64 * 64];
    int t = threadIdx.x;
    float ob = 1.0f - beta;
#pragma unroll
    for (int i0 = 0; i0 < 4; ++i0) {
        int i = t + i0 * 256;
        float4 v = ((const float4*)W)[i];
        int base = i << 2;
        int k = base >> 6, f0 = base & 63;
        v.x = v.x * beta + ((f0 + 0 == k) ? ob : 0.f);
        v.y = v.y * beta + ((f0 + 1 == k) ? ob : 0.f);
        v.z = v.z * beta + ((f0 + 2 == k) ? ob : 0.f);
        v.w = v.w * beta + ((f0 + 3 == k) ? ob : 0.f);
        ((float4*)Bs)[i] = v;
    }
    __syncthreads();

    int lane = t & 63;
    int g = lane >> 3;         // group 0..7 (which edge within a 16-edge slab half)
    int fc = (lane & 7) << 3;  // feature chunk base
    int wave = blockIdx.x * 4 + (t >> 6);
    int nwaves = gridDim.x * 4;

    for (int node = wave; node < NN; node += nwaves) {
        int start = rp[node], end = rp[node + 1];
        float acc[8] = {};
        for (int e = start; e < end; e += 64) {
            int me = e + lane;
            int c = (me < end) ? col[me] : NN;  // sentinel row NN is all-zero
            int nb = end - e;
            if (nb > 64) nb = 64;
            int it2 = (nb + 15) >> 4;
            for (int j = 0; j < it2; ++j) {
                int c0 = __shfl(c, j * 16 + g, 64);
                int c1 = __shfl(c, j * 16 + 8 + g, 64);
                float4 r0 = *(const float4*)(hin + ((size_t)c0 << 6) + fc);
                float4 r1 = *(const float4*)(hin + ((size_t)c1 << 6) + fc);
                const __half2* h0 = (const __half2*)&r0;
                const __half2* h1 = (const __half2*)&r1;
#pragma unroll
                for (int q = 0; q < 4; ++q) {
                    float2 f = __half22float2(h0[q]);
                    acc[2 * q] += f.x;
                    acc[2 * q + 1] += f.y;
                }
#pragma unroll
                for (int q = 0; q < 4; ++q) {
                    float2 f = __half22float2(h1[q]);
                    acc[2 * q] += f.x;
                    acc[2 * q + 1] += f.y;
                }
            }
        }
        // reduce the 8 groups (lane bits 3..5)
#pragma unroll
        for (int m = 8; m <= 32; m <<= 1)
#pragma unroll
            for (int q = 0; q < 8; ++q) acc[q] += __shfl_xor(acc[q], m, 64);
        // self loop (added once, post-butterfly; identical across groups)
        {
            float4 r = *(const float4*)(hin + ((size_t)node << 6) + fc);
            const __half2* hh = (const __half2*)&r;
#pragma unroll
            for (int q = 0; q < 4; ++q) {
                float2 f = __half22float2(hh[q]);
                acc[2 * q] += f.x;
                acc[2 * q + 1] += f.y;
            }
        }
        float di = dinv[node];
        const float4* xp = (const float4*)(x0 + ((size_t)node << 6) + fc);
        float4 xa = xp[0], xb = xp[1];
        float xs[8] = {xa.x, xa.y, xa.z, xa.w, xb.x, xb.y, xb.z, xb.w};
#pragma unroll
        for (int q = 0; q < 8; ++q) acc[q] = 0.5f * fmaf(di, acc[q], xs[q]);
        // o[lane] = sum_k s[k] * Bhat[k][lane]; s[k] lives in lane k>>3, reg k&7
        float o = 0.f;
#pragma unroll
        for (int k = 0; k < 64; ++k) {
            float sk = __shfl(acc[k & 7], k >> 3, 64);  // uniform lane -> v_readlane
            o = fmaf(sk, Bs[(k << 6) + lane], o);
        }
        float hv = eluf(o) + o;
        hout[(size_t)node * HH + lane] = __float2half(hv * di);
        if (w32) hout32[(size_t)node * HH + lane] = hv;
    }
}

// ---------------- dense GEMM for input/output layers ----------------
// MODE 0: out32 = elu(A@B + bias); out16 = half(dinv[r] * out32)   (KTOT=256)
// MODE 2: out32 = A@B + bias                                       (KTOT=64)

template <int KTOT, int MODE>
__global__ __launch_bounds__(256) void gemm_k(const float* __restrict__ A,
                                              const float* __restrict__ B,
                                              const float* __restrict__ bias,
                                              const float* __restrict__ dinvp,
                                              float* __restrict__ out32,
                                              __half* __restrict__ out16) {
    __shared__ float ss[64][68];
    __shared__ float ws[64][64];
    int t = threadIdx.x;
    int row0 = blockIdx.x * 64;
    int tx = t & 15, ty = t >> 4;
    float acc[4][4] = {};

    for (int kc = 0; kc < KTOT; kc += 64) {
#pragma unroll
        for (int i = 0; i < 4; ++i) {
            int linear = t + i * 256;
            int r = linear >> 4, q = linear & 15;
            int grow = row0 + r;
            float4 v = make_float4(0.f, 0.f, 0.f, 0.f);
            if (grow < NN) v = *(const float4*)&A[(size_t)grow * KTOT + kc + q * 4];
            *(float4*)&ss[r][q * 4] = v;
        }
#pragma unroll
        for (int i = 0; i < 4; ++i) {
            int linear = t + i * 256;
            int r = linear >> 4, q = linear & 15;
            *(float4*)&ws[r][q * 4] = *(const float4*)&B[(size_t)(kc + r) * 64 + q * 4];
        }
        __syncthreads();
#pragma unroll
        for (int k = 0; k < 64; k += 4) {
            float4 af[4], bf[4];
            af[0] = *(const float4*)&ss[ty * 4 + 0][k];
            af[1] = *(const float4*)&ss[ty * 4 + 1][k];
            af[2] = *(const float4*)&ss[ty * 4 + 2][k];
            af[3] = *(const float4*)&ss[ty * 4 + 3][k];
            bf[0] = *(const float4*)&ws[k + 0][tx * 4];
            bf[1] = *(const float4*)&ws[k + 1][tx * 4];
            bf[2] = *(const float4*)&ws[k + 2][tx * 4];
            bf[3] = *(const float4*)&ws[k + 3][tx * 4];
            const float* A4 = (const float*)af;
            const float* B4 = (const float*)bf;
#pragma unroll
            for (int i = 0; i < 4; ++i)
#pragma unroll
                for (int kk = 0; kk < 4; ++kk)
#pragma unroll
                    for (int j = 0; j < 4; ++j)
                        acc[i][j] = fmaf(A4[i * 4 + kk], B4[kk * 4 + j], acc[i][j]);
        }
        __syncthreads();
    }

#pragma unroll
    for (int i = 0; i < 4; ++i) {
        int r = row0 + ty * 4 + i;
        if (r >= NN) continue;
        float4 o;
        float* op = (float*)&o;
#pragma unroll
        for (int j = 0; j < 4; ++j) {
            float xv = acc[i][j] + bias[tx * 4 + j];
            if (MODE == 0) xv = eluf(xv);
            op[j] = xv;
        }
        *(float4*)&out32[(size_t)r * 64 + tx * 4] = o;
        if (MODE == 0) {
            float dv = dinvp[r];
            __half2* hp = (__half2*)&out16[(size_t)r * 64 + tx * 4];
            hp[0] = __floats2half2_rn(o.x * dv, o.y * dv);
            hp[1] = __floats2half2_rn(o.z * dv, o.w * dv);
        }
    }
}

// ---------------- launch ----------------

extern "C" void kernel_launch(void* const* d_in, const int* in_sizes, int n_in, void* d_out,
                              int out_size, void* d_ws, size_t ws_size, hipStream_t stream) {
    const float* x = (const float*)d_in[0];
    const int* ei = (const int*)d_in[1];
    const float* w_in = (const float*)d_in[2];
    const float* b_in = (const float*)d_in[3];
    const float* w_layers = (const float*)d_in[4];
    const float* w_out = (const float*)d_in[5];
    const float* b_out = (const float*)d_in[6];
    float* out = (float*)d_out;

    char* p = (char*)d_ws;
    auto alloc = [&](size_t bytes) -> char* {
        char* r = p;
        p += (bytes + 255) & ~(size_t)255;
        return r;
    };
    int* counts = (int*)alloc((size_t)NN * 4);
    int* fill = (int*)alloc((size_t)NN * 4);
    int* rp = (int*)alloc((size_t)(NN + 1) * 4);
    int* partial = (int*)alloc(128 * 4);
    float* dinv = (float*)alloc((size_t)NN * 4);
    int* colA = (int*)alloc((size_t)EE * 4);
    float* x0 = (float*)alloc((size_t)NN * HH * 4);           // fp32 residual
    __half* x0h = (__half*)alloc((size_t)(NN + 1) * HH * 2);  // scaled gather buf A
    __half* hA = (__half*)alloc((size_t)(NN + 1) * HH * 2);   // scaled gather buf B
    float* sbuf = (float*)alloc((size_t)NN * HH * 4);         // fp32 final h

    const int* srcA = ei;
    const int* dstA = ei + EE;

    hipMemsetAsync(counts, 0, (size_t)NN * 4, stream);
    hipMemsetAsync(fill, 0, (size_t)NN * 4, stream);
    count_edges_k<<<(EE + 255) / 256, 256, 0, stream>>>(dstA, counts);
    scan_block_k<<<NBLK, 256, 0, stream>>>(counts, rp, partial, dinv);
    scan_top_k<<<1, 128, 0, stream>>>(partial);
    scan_add_k<<<(NN + 1 + 255) / 256, 256, 0, stream>>>(rp, partial);
    scatter_k<<<(EE + 255) / 256, 256, 0, stream>>>(srcA, dstA, rp, fill, colA);
    init_sent_k<<<1, 128, 0, stream>>>(x0h, hA);

    // x0 = elu(x @ w_in + b_in);  x0h = half(dinv * x0)
    gemm_k<256, 0><<<(NN + 63) / 64, 256, 0, stream>>>(x, w_in, b_in, dinv, x0, x0h);

    for (int l = 0; l < LL; ++l) {
        float beta = (float)log(1.0 / (double)(l + 1) + 1.0);
        const __half* hin = (l & 1) ? hA : x0h;  // l=0 reads x0h
        __half* hout = (l & 1) ? x0h : hA;
        layer_k<<<2048, 256, 0, stream>>>(rp, colA, dinv, hin, x0,
                                          w_layers + (size_t)l * 64 * 64, beta, hout, sbuf,
                                          l == LL - 1);
    }
    gemm_k<64, 2><<<(NN + 63) / 64, 256, 0, stream>>>(sbuf, w_out, b_out, nullptr, out, nullptr);
}